// Round 7
// baseline (261.035 us; speedup 1.0000x reference)
//
#include <hip/hip_runtime.h>
#include <math.h>

#define B 64
#define D 256
#define M 8000
#define N 32
#define LG_LD 8000
#define VOCAB 50000

typedef unsigned short u16;
typedef __bf16 bf16x8 __attribute__((ext_vector_type(8)));
typedef float fx4 __attribute__((ext_vector_type(4)));

#define STR_E  264   // u16 stride of sE rows (n-major)
#define STR_P  40    // u16 stride of sP rows (b-major)
// sET interleaved layout: u16 idx of (d, slot) = (d>>2)*136 + (slot>>3)*32 + (d&3)*8 + (slot&7)
// entry-phase slot = sigma(n) = 4*(n&7) + (n>>3); key-phase slot2(m) = 2*(m&7) + (m>>3)

static __device__ __forceinline__ u16 f2bf(float x) {
    unsigned int u = __float_as_uint(x);
    u += 0x7FFFu + ((u >> 16) & 1u);
    return (u16)(u >> 16);
}
static __device__ __forceinline__ float bf2f(u16 h) {
    return __uint_as_float(((unsigned)h) << 16);
}
static __device__ __forceinline__ uint4 pack8(float4 va, float4 vb, float msk) {
    unsigned p0 = (unsigned)f2bf(va.x * msk) | ((unsigned)f2bf(va.y * msk) << 16);
    unsigned p1 = (unsigned)f2bf(va.z * msk) | ((unsigned)f2bf(va.w * msk) << 16);
    unsigned p2 = (unsigned)f2bf(vb.x * msk) | ((unsigned)f2bf(vb.y * msk) << 16);
    unsigned p3 = (unsigned)f2bf(vb.z * msk) | ((unsigned)f2bf(vb.w * msk) << 16);
    return make_uint4(p0, p1, p2, p3);
}

// lgkm-only barrier: LDS visibility without draining in-flight global loads
// (__syncthreads forces vmcnt(0)). No barrier here protects a global dependency.
#define BARRIER_LGKM() do {                                   \
    asm volatile("s_waitcnt lgkmcnt(0)" ::: "memory");        \
    __builtin_amdgcn_s_barrier();                             \
    asm volatile("" ::: "memory");                            \
} while (0)

// ---- k_prep_all: ONE kernel, five independent block ranges:
//      0..6249    : emb fp32 -> embb bf16 stream (row 0 zeroed = pre-applied pad mask)
//      6250..7249 : keb gather straight from fp32 emb (mask+pack here)
//      7250..7257 : qbf conv
//      7258..7321 : vq proj
//      7322..7323 : zero keb pad rows 8000..8015 (EPB=8 blocks read 16 keb rows)
__global__ __launch_bounds__(256) void k_prep_all(const int* __restrict__ keys,
                                                  const float* __restrict__ emb,
                                                  const float* __restrict__ q,
                                                  const float* __restrict__ W,
                                                  const float* __restrict__ bias,
                                                  u16* __restrict__ embb,
                                                  u16* __restrict__ qbf,
                                                  u16* __restrict__ keb,
                                                  u16* __restrict__ vqb) {
    __shared__ float qs[D];
    int t = threadIdx.x, bid = blockIdx.x;
    if (bid < 6250) {
        size_t idx = (size_t)bid * 2048 + (size_t)t * 8;
        float4 v0 = *(const float4*)(emb + idx);
        float4 v1 = *(const float4*)(emb + idx + 4);
        float msk = (idx < D) ? 0.f : 1.f;   // row 0 = PAD row -> zeros
        uint4 pk = pack8(v0, v1, msk);
        *(uint4*)(embb + idx) = pk;
    } else if (bid < 7250) {
        int c = (bid - 6250) * 256 + t;   // 8000*32 chunks of 8 elems
        int j = c >> 5, sp = c & 31;
        int id = keys[j];
        const float* rp = emb + (size_t)id * D + sp * 8;
        float4 v0 = *(const float4*)rp;
        float4 v1 = *(const float4*)(rp + 4);
        float msk = (id != 0) ? 1.f : 0.f;
        uint4 pk = pack8(v0, v1, msk);
        *(uint4*)(keb + (size_t)j * D + sp * 8) = pk;
    } else if (bid < 7258) {
        size_t idx = (size_t)(bid - 7250) * 2048 + (size_t)t * 8;
        float4 v0 = *(const float4*)(q + idx);
        float4 v1 = *(const float4*)(q + idx + 4);
        uint4 pk = pack8(v0, v1, 1.f);
        *(uint4*)(qbf + idx) = pk;
    } else if (bid < 7322) {
        int b = bid - 7258;
        qs[t] = q[b * D + t];
        __syncthreads();
        const float* wr = W + t * D;
        float acc = bias[t];
#pragma unroll 8
        for (int k = 0; k < D; k += 4) {
            float4 w4 = *(const float4*)(wr + k);
            acc += qs[k] * w4.x + qs[k + 1] * w4.y + qs[k + 2] * w4.z + qs[k + 3] * w4.w;
        }
        vqb[b * D + t] = f2bf(acc);
    } else {
        int idx = (bid - 7322) * 256 + t;   // 0..511 -> 16 rows x 256 u16
        *(uint4*)(keb + (size_t)8000 * D + (size_t)idx * 8) = make_uint4(0u, 0u, 0u, 0u);
    }
}

// ---- k_heavy_s<EPB_>: fused logits + flash stats + per-entry value attention +
//      numK mini-PV.  SINGLE-buffered sE/sET (two lgkm barriers per entry) to cut
//      LDS to 40,448 B (EPB=8) -> 4 blocks/CU at 1000 blocks = ~2x occupancy.
//      EPB_=16 instantiation is the ws-size fallback (500 blocks, grid-limited).
//      Inner compute (ea/eb/sP/softmax/MFMA) byte-identical to the proven R5/R6 body.
template <int EPB_>
__global__ __launch_bounds__(256, 4) void k_heavy_s(const int* __restrict__ entries,
                                                    const u16* __restrict__ embb,
                                                    const u16* __restrict__ vqb,
                                                    const u16* __restrict__ qbf,
                                                    const u16* __restrict__ keb,
                                                    float* __restrict__ lg,
                                                    u16* __restrict__ numCp,
                                                    u16* __restrict__ numKp,
                                                    float* __restrict__ mLp,
                                                    float* __restrict__ denLp) {
    __shared__ __align__(16) u16 sEu[N * STR_E];    // 16,896 B (single buffer)
    __shared__ __align__(16) u16 sETu[64 * 136];    // 17,408 B (single buffer)
    __shared__ __align__(16) u16 sPu[B * STR_P];    //  5,120 B
    __shared__ u16 sw16[EPB_][B];                   //  1,024 B (EPB=8) / 2,048 (16)

    int t = threadIdx.x;
    int lane = t & 63, l = lane & 15, q = lane >> 4, w = t >> 6;
    int b0 = 16 * w;
    int sp = t & 31, n0 = t >> 5;
    int m0 = blockIdx.x * EPB_;
    int bb = t & 63, y = t >> 6;

    // ---- earliest: ids(e0) + bf16 gather(e0) — flies underneath the fused logits ----
    int idn[4];
    uint4 pfF[4];   // 4 rows x 16 B (8 bf16 per row-chunk, pre-masked)
#pragma unroll
    for (int i = 0; i < 4; ++i) idn[i] = entries[m0 * N + n0 + 8 * i];
#pragma unroll
    for (int i = 0; i < 4; ++i)
        pfF[i] = *(const uint4*)(embb + (size_t)idn[i] * D + sp * 8);

    // ---- fused logits: aL[r] = lg[b0+4q+r][m0+l]  (16 m x 64 b tile).
    //      For EPB_=8 the upper 8 m-columns (l>=8) are neighbor/pad rows: computed
    //      but masked out of stats and stores. keb rows 8000..8015 are zero-padded.
    fx4 zero4 = {0.f, 0.f, 0.f, 0.f};
    fx4 aL = zero4;
#pragma unroll
    for (int s = 0; s < 8; ++s) {
        bf16x8 a  = *(const bf16x8*)(qbf + (size_t)(b0 + l) * D + 32 * s + 8 * q);
        bf16x8 bq = *(const bf16x8*)(keb + (size_t)(m0 + l) * D + 32 * s + 8 * q);
        aL = __builtin_amdgcn_mfma_f32_16x16x32_bf16(a, bq, aL, 0, 0, 0);
    }
    if (l < EPB_) {
#pragma unroll
        for (int r = 0; r < 4; ++r)
            lg[(size_t)(b0 + 4 * q + r) * LG_LD + m0 + l] = aL[r];
    }

    // ---- flash stats via 16-lane shuffles (masked to own EPB_ rows) ----
#pragma unroll
    for (int r = 0; r < 4; ++r) {
        float v = (l < EPB_) ? aL[r] : -INFINITY;
        float m_ = v;
        m_ = fmaxf(m_, __shfl_xor(m_, 1));
        m_ = fmaxf(m_, __shfl_xor(m_, 2));
        m_ = fmaxf(m_, __shfl_xor(m_, 4));
        m_ = fmaxf(m_, __shfl_xor(m_, 8));
        float wv = __expf(aL[r] - m_);
        if (l < EPB_) sw16[l][b0 + 4 * q + r] = f2bf(wv);   // wave-private columns
        float d_ = (l < EPB_) ? wv : 0.f;
        d_ += __shfl_xor(d_, 1);
        d_ += __shfl_xor(d_, 2);
        d_ += __shfl_xor(d_, 4);
        d_ += __shfl_xor(d_, 8);
        if (l == 0) {
            mLp[blockIdx.x * B + b0 + 4 * q + r] = m_;
            denLp[blockIdx.x * B + b0 + 4 * q + r] = d_;
        }
    }

    // persistent vq B-fragments
    bf16x8 vqf[8];
#pragma unroll
    for (int s = 0; s < 8; ++s)
        vqf[s] = *(const bf16x8*)(vqb + (b0 + l) * D + 32 * s + 8 * q);

    fx4 acc[16];
#pragma unroll
    for (int dt = 0; dt < 16; ++dt) acc[dt] = zero4;

    // ---- prologue: stage e0; gather(e1)->pfF; idn <- ids(e2) ----
    {
#pragma unroll
        for (int i = 0; i < 4; ++i)
            *(uint4*)&sEu[(n0 + 8 * i) * STR_E + sp * 8] = pfF[i];
#pragma unroll
        for (int j = 0; j < 8; ++j) {
            unsigned a0 = (((unsigned*)&pfF[0])[j >> 1] >> ((j & 1) * 16)) & 0xFFFFu;
            unsigned a1 = (((unsigned*)&pfF[1])[j >> 1] >> ((j & 1) * 16)) & 0xFFFFu;
            unsigned a2 = (((unsigned*)&pfF[2])[j >> 1] >> ((j & 1) * 16)) & 0xFFFFu;
            unsigned a3 = (((unsigned*)&pfF[3])[j >> 1] >> ((j & 1) * 16)) & 0xFFFFu;
            uint2 pr = make_uint2(a0 | (a1 << 16), a2 | (a3 << 16));
            int off = (2 * sp + (j >> 2)) * 136 + (n0 >> 1) * 32 + (j & 3) * 8 + (n0 & 1) * 4;
            *(uint2*)&sETu[off] = pr;
        }
    }
#pragma unroll
    for (int i = 0; i < 4; ++i) idn[i] = entries[(m0 + 1) * N + n0 + 8 * i];
#pragma unroll
    for (int i = 0; i < 4; ++i)
        pfF[i] = *(const uint4*)(embb + (size_t)idn[i] * D + sp * 8);
#pragma unroll
    for (int i = 0; i < 4; ++i) idn[i] = entries[(m0 + 2) * N + n0 + 8 * i];

    int offL = (l >> 2) * 136 + (l & 3) * 8;

    // ---- entry loop: single buffer, 2 lgkm-only barriers per entry ----
#pragma unroll 2
    for (int e = 0; e < EPB_; ++e) {
        BARRIER_LGKM();   // stage(e) visible to all waves; gathers stay in flight
        fx4 accS[2];
        accS[0] = zero4; accS[1] = zero4;
#pragma unroll
        for (int T = 0; T < 2; ++T)
#pragma unroll
            for (int s = 0; s < 8; ++s) {
                bf16x8 ea = *(const bf16x8*)&sEu[(16 * T + l) * STR_E + 32 * s + 8 * q];
                accS[T] = __builtin_amdgcn_mfma_f32_16x16x32_bf16(ea, vqf[s], accS[T], 0, 0, 0);
            }
        float swb = bf2f(sw16[e][b0 + l]);
        float mx = -INFINITY;
#pragma unroll
        for (int T = 0; T < 2; ++T)
#pragma unroll
            for (int r = 0; r < 4; ++r) mx = fmaxf(mx, accS[T][r]);
        mx = fmaxf(mx, __shfl_xor(mx, 16));
        mx = fmaxf(mx, __shfl_xor(mx, 32));
        float pe[2][4], sum = 0.f;
#pragma unroll
        for (int T = 0; T < 2; ++T)
#pragma unroll
            for (int r = 0; r < 4; ++r) {
                pe[T][r] = __expf(accS[T][r] - mx);
                sum += pe[T][r];
            }
        sum += __shfl_xor(sum, 16);
        sum += __shfl_xor(sum, 32);
        float sc = swb / sum;
#pragma unroll
        for (int T = 0; T < 2; ++T)
#pragma unroll
            for (int r = 0; r < 4; ++r) {
                int nn = 16 * T + 4 * q + r;
                int slot = 4 * (nn & 7) + (nn >> 3);
                sPu[(b0 + l) * STR_P + slot] = f2bf(pe[T][r] * sc);
            }
        bf16x8 pa = *(const bf16x8*)&sPu[(b0 + l) * STR_P + 8 * q];
#pragma unroll
        for (int dt = 0; dt < 16; ++dt) {
            bf16x8 eb = *(const bf16x8*)&sETu[offL + dt * 544 + q * 32];
            acc[dt] = __builtin_amdgcn_mfma_f32_16x16x32_bf16(pa, eb, acc[dt], 0, 0, 0);
        }
        BARRIER_LGKM();   // all waves done reading sEu/sETu for entry e
        if (e < EPB_ - 1) {
            // stage entry e+1 (held in pfF)
#pragma unroll
            for (int i = 0; i < 4; ++i)
                *(uint4*)&sEu[(n0 + 8 * i) * STR_E + sp * 8] = pfF[i];
#pragma unroll
            for (int j = 0; j < 8; ++j) {
                unsigned a0 = (((unsigned*)&pfF[0])[j >> 1] >> ((j & 1) * 16)) & 0xFFFFu;
                unsigned a1 = (((unsigned*)&pfF[1])[j >> 1] >> ((j & 1) * 16)) & 0xFFFFu;
                unsigned a2 = (((unsigned*)&pfF[2])[j >> 1] >> ((j & 1) * 16)) & 0xFFFFu;
                unsigned a3 = (((unsigned*)&pfF[3])[j >> 1] >> ((j & 1) * 16)) & 0xFFFFu;
                uint2 pr = make_uint2(a0 | (a1 << 16), a2 | (a3 << 16));
                int off = (2 * sp + (j >> 2)) * 136 + (n0 >> 1) * 32 + (j & 3) * 8 + (n0 & 1) * 4;
                *(uint2*)&sETu[off] = pr;
            }
            if (e < EPB_ - 2) {
#pragma unroll
                for (int i = 0; i < 4; ++i)
                    pfF[i] = *(const uint4*)(embb + (size_t)idn[i] * D + sp * 8);
                if (e < EPB_ - 3) {
#pragma unroll
                    for (int i = 0; i < 4; ++i) idn[i] = entries[(m0 + e + 3) * N + n0 + 8 * i];
                }
            }
        }
    }

    // ---- store numC partial ----
    u16* ncp = numCp + (size_t)blockIdx.x * (B * D);
#pragma unroll
    for (int dt = 0; dt < 16; ++dt)
#pragma unroll
        for (int r = 0; r < 4; ++r)
            ncp[(b0 + 4 * q + r) * D + 16 * dt + l] = f2bf(acc[dt][r]);

    // ---- numK mini-PV: key rows at slot2(m) = 2*(m&7)+(m>>3); unused slots carry
    //      stale-but-finite data zeroed by 0-weights in P (proven invariant) ----
    BARRIER_LGKM();   // all waves done reading sETu/sPu
    if constexpr (EPB_ == 16) {
        int rp = t >> 5;   // 0..7
        uint4 ka = *(const uint4*)(keb + (size_t)(m0 + rp) * D + sp * 8);
        uint4 kb = *(const uint4*)(keb + (size_t)(m0 + rp + 8) * D + sp * 8);
#pragma unroll
        for (int j = 0; j < 8; ++j) {
            unsigned a0 = (((unsigned*)&ka)[j >> 1] >> ((j & 1) * 16)) & 0xFFFFu;
            unsigned a1 = (((unsigned*)&kb)[j >> 1] >> ((j & 1) * 16)) & 0xFFFFu;
            int d = 8 * sp + j;
            int sl = 2 * rp;   // slots 2rp, 2rp+1
            int off = (d >> 2) * 136 + (sl >> 3) * 32 + (d & 3) * 8 + (sl & 7);
            *(unsigned*)&sETu[off] = a0 | (a1 << 16);
        }
        // weights into sP (slots 0..15 = flash weights, 16..31 = 0)
#pragma unroll
        for (int i = 0; i < 4; ++i) {
            int m = 4 * i + y;
            int slot = 2 * (m & 7) + (m >> 3);
            sPu[bb * STR_P + slot] = sw16[m][bb];
        }
        *(uint2*)&sPu[bb * STR_P + 16 + 4 * y] = make_uint2(0u, 0u);
    } else {
        // EPB_=8: 8 key rows -> even slots 2rp; odd + upper slots zero-weighted
        int rp = t >> 5;   // 0..7
        uint4 ka = *(const uint4*)(keb + (size_t)(m0 + rp) * D + sp * 8);
#pragma unroll
        for (int j = 0; j < 8; ++j) {
            unsigned a0 = (((unsigned*)&ka)[j >> 1] >> ((j & 1) * 16)) & 0xFFFFu;
            int d = 8 * sp + j;
            int sl = 2 * rp;
            int off = (d >> 2) * 136 + (sl >> 3) * 32 + (d & 3) * 8 + (sl & 7);
            *(unsigned*)&sETu[off] = a0;   // slot sl = key, slot sl+1 = 0
        }
        // thread (bb,y) owns slots [8y, 8y+8): weights at even slots 2m (m=4y+j, y<2)
#pragma unroll
        for (int j = 0; j < 4; ++j) {
            unsigned val = 0u;
            if (y < 2) val = (unsigned)sw16[4 * y + j][bb];
            *(unsigned*)&sPu[bb * STR_P + 8 * y + 2 * j] = val;
        }
    }
    BARRIER_LGKM();
    fx4 acc2[16];
#pragma unroll
    for (int dt = 0; dt < 16; ++dt) acc2[dt] = zero4;
    {
        bf16x8 pa2 = *(const bf16x8*)&sPu[(b0 + l) * STR_P + 8 * q];
#pragma unroll
        for (int dt = 0; dt < 16; ++dt) {
            bf16x8 eb2 = *(const bf16x8*)&sETu[offL + dt * 544 + q * 32];
            acc2[dt] = __builtin_amdgcn_mfma_f32_16x16x32_bf16(pa2, eb2, acc2[dt], 0, 0, 0);
        }
    }
    u16* nkp = numKp + (size_t)blockIdx.x * (B * D);
#pragma unroll
    for (int dt = 0; dt < 16; ++dt)
#pragma unroll
        for (int r = 0; r < 4; ++r)
            nkp[(b0 + 4 * q + r) * D + 16 * dt + l] = f2bf(acc2[dt][r]);
}

// ---- k_comb2t<NBLK_>: fused global stats + NBLK_-way partial reduce -> o_k, comb ----
template <int NBLK_>
__global__ __launch_bounds__(256) void k_comb2t(const u16* __restrict__ numCp,
                                                const u16* __restrict__ numKp,
                                                const float* __restrict__ mLp,
                                                const float* __restrict__ denLp,
                                                float* __restrict__ o_k,
                                                float* __restrict__ comb) {
    __shared__ float sscale[NBLK_];
    __shared__ float red[256];
    __shared__ float sro[32][33], src[32][33];
    __shared__ float srden;
    int bid = blockIdx.x;
    int b = bid >> 3, d0 = (bid & 7) * 32;
    int t = threadIdx.x;
    float mx = -INFINITY;
    for (int blk = t; blk < NBLK_; blk += 256) mx = fmaxf(mx, mLp[blk * B + b]);
    red[t] = mx;
    __syncthreads();
    for (int s = 128; s > 0; s >>= 1) {
        if (t < s) red[t] = fmaxf(red[t], red[t + s]);
        __syncthreads();
    }
    float Mg = red[0];
    __syncthreads();
    float ds = 0.f;
    for (int blk = t; blk < NBLK_; blk += 256) {
        float sc = __expf(mLp[blk * B + b] - Mg);
        sscale[blk] = sc;
        ds += sc * denLp[blk * B + b];
    }
    red[t] = ds;
    __syncthreads();
    for (int s = 128; s > 0; s >>= 1) {
        if (t < s) red[t] += red[t + s];
        __syncthreads();
    }
    if (t == 0) srden = 1.f / red[0];
    __syncthreads();
    int v = t & 7, s = t >> 3;
    float ao[4] = {0.f, 0.f, 0.f, 0.f}, ac[4] = {0.f, 0.f, 0.f, 0.f};
    for (int blk = s; blk < NBLK_; blk += 32) {
        float sc = sscale[blk];
        size_t i = (size_t)blk * (B * D) + (size_t)b * D + d0 + v * 4;
        uint2 kk = *(const uint2*)(numKp + i);
        uint2 cc = *(const uint2*)(numCp + i);
        ao[0] += sc * bf2f((u16)(kk.x & 0xFFFFu));
        ao[1] += sc * bf2f((u16)(kk.x >> 16));
        ao[2] += sc * bf2f((u16)(kk.y & 0xFFFFu));
        ao[3] += sc * bf2f((u16)(kk.y >> 16));
        ac[0] += sc * bf2f((u16)(cc.x & 0xFFFFu));
        ac[1] += sc * bf2f((u16)(cc.x >> 16));
        ac[2] += sc * bf2f((u16)(cc.y & 0xFFFFu));
        ac[3] += sc * bf2f((u16)(cc.y >> 16));
    }
#pragma unroll
    for (int k = 0; k < 4; ++k) {
        sro[s][v * 4 + k] = ao[k];
        src[s][v * 4 + k] = ac[k];
    }
    __syncthreads();
    if (t < 32) {
        float so = 0.f, sc2 = 0.f;
#pragma unroll
        for (int k2 = 0; k2 < 32; ++k2) { so += sro[k2][t]; sc2 += src[k2][t]; }
        float rd = srden;
        o_k[b * D + d0 + t] = so * rd;
        comb[b * D + d0 + t] = sc2 * rd;
    }
}

// ==================== launcher ====================

extern "C" void kernel_launch(void* const* d_in, const int* in_sizes, int n_in,
                              void* d_out, int out_size, void* d_ws, size_t ws_size,
                              hipStream_t stream) {
    const int*   keys    = (const int*)d_in[0];
    const int*   entries = (const int*)d_in[1];
    const float* query   = (const float*)d_in[2];
    const float* wordemb = (const float*)d_in[3];
    const float* qproj_w = (const float*)d_in[4];
    const float* qproj_b = (const float*)d_in[5];

    float* out  = (float*)d_out;
    float* o_k  = out;
    float* lg   = out + B * D;
    float* comb = out + B * D + B * M;

    char* wsb = (char*)d_ws;
    u16* embb = (u16*)wsb;                          // 25,600,000 B (bf16 table, row0=0)
    u16* keb  = (u16*)(wsb + 25600000);             //  4,104,192 B (8016 rows, pad zeroed)
    u16* qbf  = (u16*)(wsb + 29704192);             //     32,768 B
    u16* vqb  = (u16*)(wsb + 29736960);             //     32,768 B
    char* dyn = wsb + 29769728;

    const size_t szC8 = (size_t)1000 * B * D * 2;   // 32,768,000
    const size_t szS8 = (size_t)1000 * B * 4;       //    256,000
    const size_t need8 = 29769728 + 2 * szC8 + 2 * szS8;   // 95,817,728

    k_prep_all<<<7324, 256, 0, stream>>>(keys, wordemb, query, qproj_w, qproj_b,
                                         embb, qbf, keb, vqb);
    if (ws_size >= need8) {
        u16*   numCp = (u16*)dyn;
        u16*   numKp = (u16*)(dyn + szC8);
        float* mLp   = (float*)(dyn + 2 * szC8);
        float* denLp = (float*)(dyn + 2 * szC8 + szS8);
        k_heavy_s<8><<<1000, 256, 0, stream>>>(entries, embb, vqb, qbf, keb, lg,
                                               numCp, numKp, mLp, denLp);
        k_comb2t<1000><<<512, 256, 0, stream>>>(numCp, numKp, mLp, denLp, o_k, comb);
    } else {
        const size_t szC = (size_t)500 * B * D * 2;
        const size_t szS = (size_t)500 * B * 4;
        u16*   numCp = (u16*)dyn;
        u16*   numKp = (u16*)(dyn + szC);
        float* mLp   = (float*)(dyn + 2 * szC);
        float* denLp = (float*)(dyn + 2 * szC + szS);
        k_heavy_s<16><<<500, 256, 0, stream>>>(entries, embb, vqb, qbf, keb, lg,
                                               numCp, numKp, mLp, denLp);
        k_comb2t<500><<<512, 256, 0, stream>>>(numCp, numKp, mLp, denLp, o_k, comb);
    }
}

// Round 8
// 190.361 us; speedup vs baseline: 1.3713x; 1.3713x over previous
//
#include <hip/hip_runtime.h>
#include <math.h>

#define B 64
#define D 256
#define M 8000
#define N 32
#define LG_LD 8000
#define VOCAB 50000

typedef unsigned short u16;
typedef __bf16 bf16x8 __attribute__((ext_vector_type(8)));
typedef float fx4 __attribute__((ext_vector_type(4)));

#define STR_E  264   // u16 stride of sE rows (n-major)
#define STR_P  40    // u16 stride of sP rows (b-major)
// sET interleaved layout: u16 idx of (d, slot) = (d>>2)*136 + (slot>>3)*32 + (d&3)*8 + (slot&7)
// entry-phase slot = sigma(n) = 4*(n&7) + (n>>3); key-phase slot2(m) = 2*(m&7) + (m>>3)

static __device__ __forceinline__ u16 f2bf(float x) {
    unsigned int u = __float_as_uint(x);
    u += 0x7FFFu + ((u >> 16) & 1u);
    return (u16)(u >> 16);
}
static __device__ __forceinline__ float bf2f(u16 h) {
    return __uint_as_float(((unsigned)h) << 16);
}
static __device__ __forceinline__ uint4 pack8(float4 va, float4 vb, float msk) {
    unsigned p0 = (unsigned)f2bf(va.x * msk) | ((unsigned)f2bf(va.y * msk) << 16);
    unsigned p1 = (unsigned)f2bf(va.z * msk) | ((unsigned)f2bf(va.w * msk) << 16);
    unsigned p2 = (unsigned)f2bf(vb.x * msk) | ((unsigned)f2bf(vb.y * msk) << 16);
    unsigned p3 = (unsigned)f2bf(vb.z * msk) | ((unsigned)f2bf(vb.w * msk) << 16);
    return make_uint4(p0, p1, p2, p3);
}

// lgkm-only barrier: LDS visibility without draining in-flight global loads
// (__syncthreads forces vmcnt(0)). No barrier here protects a global dependency.
#define BARRIER_LGKM() do {                                   \
    asm volatile("s_waitcnt lgkmcnt(0)" ::: "memory");        \
    __builtin_amdgcn_s_barrier();                             \
    asm volatile("" ::: "memory");                            \
} while (0)

// ---- k_prep_all: ONE kernel, five independent block ranges:
//      0..6249    : emb fp32 -> embb bf16 stream (row 0 zeroed = pre-applied pad mask)
//      6250..7249 : keb gather straight from fp32 emb (mask+pack here)
//      7250..7257 : qbf conv
//      7258..7321 : vq proj
//      7322..7323 : zero keb pad rows 8000..8015 (EPB=8 blocks read 16 keb rows)
__global__ __launch_bounds__(256) void k_prep_all(const int* __restrict__ keys,
                                                  const float* __restrict__ emb,
                                                  const float* __restrict__ q,
                                                  const float* __restrict__ W,
                                                  const float* __restrict__ bias,
                                                  u16* __restrict__ embb,
                                                  u16* __restrict__ qbf,
                                                  u16* __restrict__ keb,
                                                  u16* __restrict__ vqb) {
    __shared__ float qs[D];
    int t = threadIdx.x, bid = blockIdx.x;
    if (bid < 6250) {
        size_t idx = (size_t)bid * 2048 + (size_t)t * 8;
        float4 v0 = *(const float4*)(emb + idx);
        float4 v1 = *(const float4*)(emb + idx + 4);
        float msk = (idx < D) ? 0.f : 1.f;   // row 0 = PAD row -> zeros
        uint4 pk = pack8(v0, v1, msk);
        *(uint4*)(embb + idx) = pk;
    } else if (bid < 7250) {
        int c = (bid - 6250) * 256 + t;   // 8000*32 chunks of 8 elems
        int j = c >> 5, sp = c & 31;
        int id = keys[j];
        const float* rp = emb + (size_t)id * D + sp * 8;
        float4 v0 = *(const float4*)rp;
        float4 v1 = *(const float4*)(rp + 4);
        float msk = (id != 0) ? 1.f : 0.f;
        uint4 pk = pack8(v0, v1, msk);
        *(uint4*)(keb + (size_t)j * D + sp * 8) = pk;
    } else if (bid < 7258) {
        size_t idx = (size_t)(bid - 7250) * 2048 + (size_t)t * 8;
        float4 v0 = *(const float4*)(q + idx);
        float4 v1 = *(const float4*)(q + idx + 4);
        uint4 pk = pack8(v0, v1, 1.f);
        *(uint4*)(qbf + idx) = pk;
    } else if (bid < 7322) {
        int b = bid - 7258;
        qs[t] = q[b * D + t];
        __syncthreads();
        const float* wr = W + t * D;
        float acc = bias[t];
#pragma unroll 8
        for (int k = 0; k < D; k += 4) {
            float4 w4 = *(const float4*)(wr + k);
            acc += qs[k] * w4.x + qs[k + 1] * w4.y + qs[k + 2] * w4.z + qs[k + 3] * w4.w;
        }
        vqb[b * D + t] = f2bf(acc);
    } else {
        int idx = (bid - 7322) * 256 + t;   // 0..511 -> 16 rows x 256 u16
        *(uint4*)(keb + (size_t)8000 * D + (size_t)idx * 8) = make_uint4(0u, 0u, 0u, 0u);
    }
}

// ---- k_heavy_s<EPB_>: fused logits + flash stats + per-entry value attention +
//      numK mini-PV.  SINGLE-buffered sE/sET, 40,448 B LDS at EPB=8 -> 4 blocks/CU
//      at 1000 blocks (~2x occupancy vs R6's grid-limited 500).
//      launch_bounds (256,2): R7's (256,4) forced VGPR 88->64 and the resulting
//      scratch spill exploded HBM traffic (WRITE 34->247 MB). LDS caps blocks/CU
//      at 4 on its own; the register file sustains 4 waves/SIMD at ~88 VGPR.
template <int EPB_>
__global__ __launch_bounds__(256, 2) void k_heavy_s(const int* __restrict__ entries,
                                                    const u16* __restrict__ embb,
                                                    const u16* __restrict__ vqb,
                                                    const u16* __restrict__ qbf,
                                                    const u16* __restrict__ keb,
                                                    float* __restrict__ lg,
                                                    u16* __restrict__ numCp,
                                                    u16* __restrict__ numKp,
                                                    float* __restrict__ mLp,
                                                    float* __restrict__ denLp) {
    __shared__ __align__(16) u16 sEu[N * STR_E];    // 16,896 B (single buffer)
    __shared__ __align__(16) u16 sETu[64 * 136];    // 17,408 B (single buffer)
    __shared__ __align__(16) u16 sPu[B * STR_P];    //  5,120 B
    __shared__ u16 sw16[EPB_][B];                   //  1,024 B (EPB=8) / 2,048 (16)

    int t = threadIdx.x;
    int lane = t & 63, l = lane & 15, q = lane >> 4, w = t >> 6;
    int b0 = 16 * w;
    int sp = t & 31, n0 = t >> 5;
    int m0 = blockIdx.x * EPB_;
    int bb = t & 63, y = t >> 6;

    // ---- earliest: ids(e0) + bf16 gather(e0) — flies underneath the fused logits ----
    int idn[4];
    uint4 pfF[4];   // 4 rows x 16 B (8 bf16 per row-chunk, pre-masked)
#pragma unroll
    for (int i = 0; i < 4; ++i) idn[i] = entries[m0 * N + n0 + 8 * i];
#pragma unroll
    for (int i = 0; i < 4; ++i)
        pfF[i] = *(const uint4*)(embb + (size_t)idn[i] * D + sp * 8);

    // ---- fused logits: aL[r] = lg[b0+4q+r][m0+l]  (16 m x 64 b tile).
    //      For EPB_=8 the upper 8 m-columns (l>=8) are neighbor/pad rows: computed
    //      but masked out of stats and stores. keb rows 8000..8015 are zero-padded.
    fx4 zero4 = {0.f, 0.f, 0.f, 0.f};
    fx4 aL = zero4;
#pragma unroll
    for (int s = 0; s < 8; ++s) {
        bf16x8 a  = *(const bf16x8*)(qbf + (size_t)(b0 + l) * D + 32 * s + 8 * q);
        bf16x8 bq = *(const bf16x8*)(keb + (size_t)(m0 + l) * D + 32 * s + 8 * q);
        aL = __builtin_amdgcn_mfma_f32_16x16x32_bf16(a, bq, aL, 0, 0, 0);
    }
    if (l < EPB_) {
#pragma unroll
        for (int r = 0; r < 4; ++r)
            lg[(size_t)(b0 + 4 * q + r) * LG_LD + m0 + l] = aL[r];
    }

    // ---- flash stats via 16-lane shuffles (masked to own EPB_ rows) ----
#pragma unroll
    for (int r = 0; r < 4; ++r) {
        float v = (l < EPB_) ? aL[r] : -INFINITY;
        float m_ = v;
        m_ = fmaxf(m_, __shfl_xor(m_, 1));
        m_ = fmaxf(m_, __shfl_xor(m_, 2));
        m_ = fmaxf(m_, __shfl_xor(m_, 4));
        m_ = fmaxf(m_, __shfl_xor(m_, 8));
        float wv = __expf(aL[r] - m_);
        if (l < EPB_) sw16[l][b0 + 4 * q + r] = f2bf(wv);   // wave-private columns
        float d_ = (l < EPB_) ? wv : 0.f;
        d_ += __shfl_xor(d_, 1);
        d_ += __shfl_xor(d_, 2);
        d_ += __shfl_xor(d_, 4);
        d_ += __shfl_xor(d_, 8);
        if (l == 0) {
            mLp[blockIdx.x * B + b0 + 4 * q + r] = m_;
            denLp[blockIdx.x * B + b0 + 4 * q + r] = d_;
        }
    }

    // persistent vq B-fragments
    bf16x8 vqf[8];
#pragma unroll
    for (int s = 0; s < 8; ++s)
        vqf[s] = *(const bf16x8*)(vqb + (b0 + l) * D + 32 * s + 8 * q);

    fx4 acc[16];
#pragma unroll
    for (int dt = 0; dt < 16; ++dt) acc[dt] = zero4;

    // ---- prologue: stage e0; gather(e1)->pfF; idn <- ids(e2) ----
    {
#pragma unroll
        for (int i = 0; i < 4; ++i)
            *(uint4*)&sEu[(n0 + 8 * i) * STR_E + sp * 8] = pfF[i];
#pragma unroll
        for (int j = 0; j < 8; ++j) {
            unsigned a0 = (((unsigned*)&pfF[0])[j >> 1] >> ((j & 1) * 16)) & 0xFFFFu;
            unsigned a1 = (((unsigned*)&pfF[1])[j >> 1] >> ((j & 1) * 16)) & 0xFFFFu;
            unsigned a2 = (((unsigned*)&pfF[2])[j >> 1] >> ((j & 1) * 16)) & 0xFFFFu;
            unsigned a3 = (((unsigned*)&pfF[3])[j >> 1] >> ((j & 1) * 16)) & 0xFFFFu;
            uint2 pr = make_uint2(a0 | (a1 << 16), a2 | (a3 << 16));
            int off = (2 * sp + (j >> 2)) * 136 + (n0 >> 1) * 32 + (j & 3) * 8 + (n0 & 1) * 4;
            *(uint2*)&sETu[off] = pr;
        }
    }
#pragma unroll
    for (int i = 0; i < 4; ++i) idn[i] = entries[(m0 + 1) * N + n0 + 8 * i];
#pragma unroll
    for (int i = 0; i < 4; ++i)
        pfF[i] = *(const uint4*)(embb + (size_t)idn[i] * D + sp * 8);
#pragma unroll
    for (int i = 0; i < 4; ++i) idn[i] = entries[(m0 + 2) * N + n0 + 8 * i];

    int offL = (l >> 2) * 136 + (l & 3) * 8;

    // ---- entry loop: single buffer, 2 lgkm-only barriers per entry ----
#pragma unroll 2
    for (int e = 0; e < EPB_; ++e) {
        BARRIER_LGKM();   // stage(e) visible to all waves; gathers stay in flight
        fx4 accS[2];
        accS[0] = zero4; accS[1] = zero4;
#pragma unroll
        for (int T = 0; T < 2; ++T)
#pragma unroll
            for (int s = 0; s < 8; ++s) {
                bf16x8 ea = *(const bf16x8*)&sEu[(16 * T + l) * STR_E + 32 * s + 8 * q];
                accS[T] = __builtin_amdgcn_mfma_f32_16x16x32_bf16(ea, vqf[s], accS[T], 0, 0, 0);
            }
        float swb = bf2f(sw16[e][b0 + l]);
        float mx = -INFINITY;
#pragma unroll
        for (int T = 0; T < 2; ++T)
#pragma unroll
            for (int r = 0; r < 4; ++r) mx = fmaxf(mx, accS[T][r]);
        mx = fmaxf(mx, __shfl_xor(mx, 16));
        mx = fmaxf(mx, __shfl_xor(mx, 32));
        float pe[2][4], sum = 0.f;
#pragma unroll
        for (int T = 0; T < 2; ++T)
#pragma unroll
            for (int r = 0; r < 4; ++r) {
                pe[T][r] = __expf(accS[T][r] - mx);
                sum += pe[T][r];
            }
        sum += __shfl_xor(sum, 16);
        sum += __shfl_xor(sum, 32);
        float sc = swb / sum;
#pragma unroll
        for (int T = 0; T < 2; ++T)
#pragma unroll
            for (int r = 0; r < 4; ++r) {
                int nn = 16 * T + 4 * q + r;
                int slot = 4 * (nn & 7) + (nn >> 3);
                sPu[(b0 + l) * STR_P + slot] = f2bf(pe[T][r] * sc);
            }
        bf16x8 pa = *(const bf16x8*)&sPu[(b0 + l) * STR_P + 8 * q];
#pragma unroll
        for (int dt = 0; dt < 16; ++dt) {
            bf16x8 eb = *(const bf16x8*)&sETu[offL + dt * 544 + q * 32];
            acc[dt] = __builtin_amdgcn_mfma_f32_16x16x32_bf16(pa, eb, acc[dt], 0, 0, 0);
        }
        BARRIER_LGKM();   // all waves done reading sEu/sETu for entry e
        if (e < EPB_ - 1) {
            // stage entry e+1 (held in pfF)
#pragma unroll
            for (int i = 0; i < 4; ++i)
                *(uint4*)&sEu[(n0 + 8 * i) * STR_E + sp * 8] = pfF[i];
#pragma unroll
            for (int j = 0; j < 8; ++j) {
                unsigned a0 = (((unsigned*)&pfF[0])[j >> 1] >> ((j & 1) * 16)) & 0xFFFFu;
                unsigned a1 = (((unsigned*)&pfF[1])[j >> 1] >> ((j & 1) * 16)) & 0xFFFFu;
                unsigned a2 = (((unsigned*)&pfF[2])[j >> 1] >> ((j & 1) * 16)) & 0xFFFFu;
                unsigned a3 = (((unsigned*)&pfF[3])[j >> 1] >> ((j & 1) * 16)) & 0xFFFFu;
                uint2 pr = make_uint2(a0 | (a1 << 16), a2 | (a3 << 16));
                int off = (2 * sp + (j >> 2)) * 136 + (n0 >> 1) * 32 + (j & 3) * 8 + (n0 & 1) * 4;
                *(uint2*)&sETu[off] = pr;
            }
            if (e < EPB_ - 2) {
#pragma unroll
                for (int i = 0; i < 4; ++i)
                    pfF[i] = *(const uint4*)(embb + (size_t)idn[i] * D + sp * 8);
                if (e < EPB_ - 3) {
#pragma unroll
                    for (int i = 0; i < 4; ++i) idn[i] = entries[(m0 + e + 3) * N + n0 + 8 * i];
                }
            }
        }
    }

    // ---- store numC partial ----
    u16* ncp = numCp + (size_t)blockIdx.x * (B * D);
#pragma unroll
    for (int dt = 0; dt < 16; ++dt)
#pragma unroll
        for (int r = 0; r < 4; ++r)
            ncp[(b0 + 4 * q + r) * D + 16 * dt + l] = f2bf(acc[dt][r]);

    // ---- numK mini-PV: key rows at slot2(m) = 2*(m&7)+(m>>3); unused slots carry
    //      stale-but-finite data zeroed by 0-weights in P (proven invariant) ----
    BARRIER_LGKM();   // all waves done reading sETu/sPu
    if constexpr (EPB_ == 16) {
        int rp = t >> 5;   // 0..7
        uint4 ka = *(const uint4*)(keb + (size_t)(m0 + rp) * D + sp * 8);
        uint4 kb = *(const uint4*)(keb + (size_t)(m0 + rp + 8) * D + sp * 8);
#pragma unroll
        for (int j = 0; j < 8; ++j) {
            unsigned a0 = (((unsigned*)&ka)[j >> 1] >> ((j & 1) * 16)) & 0xFFFFu;
            unsigned a1 = (((unsigned*)&kb)[j >> 1] >> ((j & 1) * 16)) & 0xFFFFu;
            int d = 8 * sp + j;
            int sl = 2 * rp;   // slots 2rp, 2rp+1
            int off = (d >> 2) * 136 + (sl >> 3) * 32 + (d & 3) * 8 + (sl & 7);
            *(unsigned*)&sETu[off] = a0 | (a1 << 16);
        }
        // weights into sP (slots 0..15 = flash weights, 16..31 = 0)
#pragma unroll
        for (int i = 0; i < 4; ++i) {
            int m = 4 * i + y;
            int slot = 2 * (m & 7) + (m >> 3);
            sPu[bb * STR_P + slot] = sw16[m][bb];
        }
        *(uint2*)&sPu[bb * STR_P + 16 + 4 * y] = make_uint2(0u, 0u);
    } else {
        // EPB_=8: 8 key rows -> even slots 2rp; odd + upper slots zero-weighted
        int rp = t >> 5;   // 0..7
        uint4 ka = *(const uint4*)(keb + (size_t)(m0 + rp) * D + sp * 8);
#pragma unroll
        for (int j = 0; j < 8; ++j) {
            unsigned a0 = (((unsigned*)&ka)[j >> 1] >> ((j & 1) * 16)) & 0xFFFFu;
            int d = 8 * sp + j;
            int sl = 2 * rp;
            int off = (d >> 2) * 136 + (sl >> 3) * 32 + (d & 3) * 8 + (sl & 7);
            *(unsigned*)&sETu[off] = a0;   // slot sl = key, slot sl+1 = 0
        }
        // thread (bb,y) owns slots [8y, 8y+8): weights at even slots 2m (m=4y+j, y<2)
#pragma unroll
        for (int j = 0; j < 4; ++j) {
            unsigned val = 0u;
            if (y < 2) val = (unsigned)sw16[4 * y + j][bb];
            *(unsigned*)&sPu[bb * STR_P + 8 * y + 2 * j] = val;
        }
    }
    BARRIER_LGKM();
    fx4 acc2[16];
#pragma unroll
    for (int dt = 0; dt < 16; ++dt) acc2[dt] = zero4;
    {
        bf16x8 pa2 = *(const bf16x8*)&sPu[(b0 + l) * STR_P + 8 * q];
#pragma unroll
        for (int dt = 0; dt < 16; ++dt) {
            bf16x8 eb2 = *(const bf16x8*)&sETu[offL + dt * 544 + q * 32];
            acc2[dt] = __builtin_amdgcn_mfma_f32_16x16x32_bf16(pa2, eb2, acc2[dt], 0, 0, 0);
        }
    }
    u16* nkp = numKp + (size_t)blockIdx.x * (B * D);
#pragma unroll
    for (int dt = 0; dt < 16; ++dt)
#pragma unroll
        for (int r = 0; r < 4; ++r)
            nkp[(b0 + 4 * q + r) * D + 16 * dt + l] = f2bf(acc2[dt][r]);
}

// ---- k_comb2t<NBLK_>: fused global stats + NBLK_-way partial reduce -> o_k, comb ----
template <int NBLK_>
__global__ __launch_bounds__(256) void k_comb2t(const u16* __restrict__ numCp,
                                                const u16* __restrict__ numKp,
                                                const float* __restrict__ mLp,
                                                const float* __restrict__ denLp,
                                                float* __restrict__ o_k,
                                                float* __restrict__ comb) {
    __shared__ float sscale[NBLK_];
    __shared__ float red[256];
    __shared__ float sro[32][33], src[32][33];
    __shared__ float srden;
    int bid = blockIdx.x;
    int b = bid >> 3, d0 = (bid & 7) * 32;
    int t = threadIdx.x;
    float mx = -INFINITY;
    for (int blk = t; blk < NBLK_; blk += 256) mx = fmaxf(mx, mLp[blk * B + b]);
    red[t] = mx;
    __syncthreads();
    for (int s = 128; s > 0; s >>= 1) {
        if (t < s) red[t] = fmaxf(red[t], red[t + s]);
        __syncthreads();
    }
    float Mg = red[0];
    __syncthreads();
    float ds = 0.f;
    for (int blk = t; blk < NBLK_; blk += 256) {
        float sc = __expf(mLp[blk * B + b] - Mg);
        sscale[blk] = sc;
        ds += sc * denLp[blk * B + b];
    }
    red[t] = ds;
    __syncthreads();
    for (int s = 128; s > 0; s >>= 1) {
        if (t < s) red[t] += red[t + s];
        __syncthreads();
    }
    if (t == 0) srden = 1.f / red[0];
    __syncthreads();
    int v = t & 7, s = t >> 3;
    float ao[4] = {0.f, 0.f, 0.f, 0.f}, ac[4] = {0.f, 0.f, 0.f, 0.f};
    for (int blk = s; blk < NBLK_; blk += 32) {
        float sc = sscale[blk];
        size_t i = (size_t)blk * (B * D) + (size_t)b * D + d0 + v * 4;
        uint2 kk = *(const uint2*)(numKp + i);
        uint2 cc = *(const uint2*)(numCp + i);
        ao[0] += sc * bf2f((u16)(kk.x & 0xFFFFu));
        ao[1] += sc * bf2f((u16)(kk.x >> 16));
        ao[2] += sc * bf2f((u16)(kk.y & 0xFFFFu));
        ao[3] += sc * bf2f((u16)(kk.y >> 16));
        ac[0] += sc * bf2f((u16)(cc.x & 0xFFFFu));
        ac[1] += sc * bf2f((u16)(cc.x >> 16));
        ac[2] += sc * bf2f((u16)(cc.y & 0xFFFFu));
        ac[3] += sc * bf2f((u16)(cc.y >> 16));
    }
#pragma unroll
    for (int k = 0; k < 4; ++k) {
        sro[s][v * 4 + k] = ao[k];
        src[s][v * 4 + k] = ac[k];
    }
    __syncthreads();
    if (t < 32) {
        float so = 0.f, sc2 = 0.f;
#pragma unroll
        for (int k2 = 0; k2 < 32; ++k2) { so += sro[k2][t]; sc2 += src[k2][t]; }
        float rd = srden;
        o_k[b * D + d0 + t] = so * rd;
        comb[b * D + d0 + t] = sc2 * rd;
    }
}

// ==================== launcher ====================

extern "C" void kernel_launch(void* const* d_in, const int* in_sizes, int n_in,
                              void* d_out, int out_size, void* d_ws, size_t ws_size,
                              hipStream_t stream) {
    const int*   keys    = (const int*)d_in[0];
    const int*   entries = (const int*)d_in[1];
    const float* query   = (const float*)d_in[2];
    const float* wordemb = (const float*)d_in[3];
    const float* qproj_w = (const float*)d_in[4];
    const float* qproj_b = (const float*)d_in[5];

    float* out  = (float*)d_out;
    float* o_k  = out;
    float* lg   = out + B * D;
    float* comb = out + B * D + B * M;

    char* wsb = (char*)d_ws;
    u16* embb = (u16*)wsb;                          // 25,600,000 B (bf16 table, row0=0)
    u16* keb  = (u16*)(wsb + 25600000);             //  4,104,192 B (8016 rows, pad zeroed)
    u16* qbf  = (u16*)(wsb + 29704192);             //     32,768 B
    u16* vqb  = (u16*)(wsb + 29736960);             //     32,768 B
    char* dyn = wsb + 29769728;

    const size_t szC8 = (size_t)1000 * B * D * 2;   // 32,768,000
    const size_t szS8 = (size_t)1000 * B * 4;       //    256,000
    const size_t need8 = 29769728 + 2 * szC8 + 2 * szS8;   // 95,817,728

    k_prep_all<<<7324, 256, 0, stream>>>(keys, wordemb, query, qproj_w, qproj_b,
                                         embb, qbf, keb, vqb);
    if (ws_size >= need8) {
        u16*   numCp = (u16*)dyn;
        u16*   numKp = (u16*)(dyn + szC8);
        float* mLp   = (float*)(dyn + 2 * szC8);
        float* denLp = (float*)(dyn + 2 * szC8 + szS8);
        k_heavy_s<8><<<1000, 256, 0, stream>>>(entries, embb, vqb, qbf, keb, lg,
                                               numCp, numKp, mLp, denLp);
        k_comb2t<1000><<<512, 256, 0, stream>>>(numCp, numKp, mLp, denLp, o_k, comb);
    } else {
        const size_t szC = (size_t)500 * B * D * 2;
        const size_t szS = (size_t)500 * B * 4;
        u16*   numCp = (u16*)dyn;
        u16*   numKp = (u16*)(dyn + szC);
        float* mLp   = (float*)(dyn + 2 * szC);
        float* denLp = (float*)(dyn + 2 * szC + szS);
        k_heavy_s<16><<<500, 256, 0, stream>>>(entries, embb, vqb, qbf, keb, lg,
                                               numCp, numKp, mLp, denLp);
        k_comb2t<500><<<512, 256, 0, stream>>>(numCp, numKp, mLp, denLp, o_k, comb);
    }
}

// Round 9
// 168.230 us; speedup vs baseline: 1.5517x; 1.1316x over previous
//
#include <hip/hip_runtime.h>
#include <math.h>

#define B 64
#define D 256
#define M 8000
#define N 32
#define LG_LD 8000
#define EPB 16          // entries per block (flash k_heavy)
#define NBLK (M / EPB)  // 500
#define VOCAB 50000

typedef unsigned short u16;
typedef __bf16 bf16x8 __attribute__((ext_vector_type(8)));
typedef float fx4 __attribute__((ext_vector_type(4)));

#define STR_E  264   // u16 stride of sE rows (n-major)  [ea reads: bank-uniform, proven]
#define STR_P  40    // u16 stride of sP rows (b-major)  [pa reads: bank-uniform]
// sET layout (ROUND 9): u16 idx of (d, slot) = (d>>2)*136 + (d&3)*32 + (slot>>3)*8 + (slot&7)
//   eb read 16B-group/phase = (l>>2)+4(l&3)+q mod 8 -> uniform 2/group = conflict-free.
//   (old layout had (slot>>3)*32 + (d&3)*8 -> 4-way conflict, the 1.2e7 counter.)
// entry-phase slot = sigma(n) = 4*(n&7) + (n>>3); key-phase slot2(m) = 2*(m&7) + (m>>3)

static __device__ __forceinline__ u16 f2bf(float x) {
    unsigned int u = __float_as_uint(x);
    u += 0x7FFFu + ((u >> 16) & 1u);
    return (u16)(u >> 16);
}
static __device__ __forceinline__ float bf2f(u16 h) {
    return __uint_as_float(((unsigned)h) << 16);
}
static __device__ __forceinline__ uint4 pack8(float4 va, float4 vb, float msk) {
    unsigned p0 = (unsigned)f2bf(va.x * msk) | ((unsigned)f2bf(va.y * msk) << 16);
    unsigned p1 = (unsigned)f2bf(va.z * msk) | ((unsigned)f2bf(va.w * msk) << 16);
    unsigned p2 = (unsigned)f2bf(vb.x * msk) | ((unsigned)f2bf(vb.y * msk) << 16);
    unsigned p3 = (unsigned)f2bf(vb.z * msk) | ((unsigned)f2bf(vb.w * msk) << 16);
    return make_uint4(p0, p1, p2, p3);
}

// lgkm-only barrier: LDS visibility without draining in-flight global loads.
#define BARRIER_LGKM() do {                                   \
    asm volatile("s_waitcnt lgkmcnt(0)" ::: "memory");        \
    __builtin_amdgcn_s_barrier();                             \
    asm volatile("" ::: "memory");                            \
} while (0)

// ---- k_prep_all: ONE kernel, four independent block ranges:
//      0..6249    : emb fp32 -> embb bf16 stream (row 0 zeroed = pre-applied pad mask)
//      6250..7249 : keb gather straight from fp32 emb (mask+pack here)
//      7250..7257 : qbf conv
//      7258..7321 : vq proj
__global__ __launch_bounds__(256) void k_prep_all(const int* __restrict__ keys,
                                                  const float* __restrict__ emb,
                                                  const float* __restrict__ q,
                                                  const float* __restrict__ W,
                                                  const float* __restrict__ bias,
                                                  u16* __restrict__ embb,
                                                  u16* __restrict__ qbf,
                                                  u16* __restrict__ keb,
                                                  u16* __restrict__ vqb) {
    __shared__ float qs[D];
    int t = threadIdx.x, bid = blockIdx.x;
    if (bid < 6250) {
        size_t idx = (size_t)bid * 2048 + (size_t)t * 8;
        float4 v0 = *(const float4*)(emb + idx);
        float4 v1 = *(const float4*)(emb + idx + 4);
        float msk = (idx < D) ? 0.f : 1.f;   // row 0 = PAD row -> zeros
        uint4 pk = pack8(v0, v1, msk);
        *(uint4*)(embb + idx) = pk;
    } else if (bid < 7250) {
        int c = (bid - 6250) * 256 + t;   // 8000*32 chunks of 8 elems
        int j = c >> 5, sp = c & 31;
        int id = keys[j];
        const float* rp = emb + (size_t)id * D + sp * 8;
        float4 v0 = *(const float4*)rp;
        float4 v1 = *(const float4*)(rp + 4);
        float msk = (id != 0) ? 1.f : 0.f;
        uint4 pk = pack8(v0, v1, msk);
        *(uint4*)(keb + (size_t)j * D + sp * 8) = pk;
    } else if (bid < 7258) {
        size_t idx = (size_t)(bid - 7250) * 2048 + (size_t)t * 8;
        float4 v0 = *(const float4*)(q + idx);
        float4 v1 = *(const float4*)(q + idx + 4);
        uint4 pk = pack8(v0, v1, 1.f);
        *(uint4*)(qbf + idx) = pk;
    } else {
        int b = bid - 7258;
        qs[t] = q[b * D + t];
        __syncthreads();
        const float* wr = W + t * D;
        float acc = bias[t];
#pragma unroll 8
        for (int k = 0; k < D; k += 4) {
            float4 w4 = *(const float4*)(wr + k);
            acc += qs[k] * w4.x + qs[k + 1] * w4.y + qs[k + 2] * w4.z + qs[k + 3] * w4.w;
        }
        vqb[b * D + t] = f2bf(acc);
    }
}

// ---- k_heavy_f: fused logits + flash stats + per-entry value attention + numK mini-PV.
//      R6 dbuf base (EPB=16, 1 syncthreads/entry, unroll 2).  ROUND 9:
//      (1) PV wave-split: wave w computes dt in {4w..4w+3} for ALL 4 batch-groups
//          (4 pa + 4 eb reads/entry/wave instead of 1 + 16) — removes the 4x
//          redundant eb reads that saturated the LDS pipe (R8: 2x occupancy = 0 gain).
//          Needs one lgkm-only barrier between sP write and PV (cross-wave reads).
//      (2) sET relayout (header) makes the eb read bank-uniform (was 4-way).
__global__ __launch_bounds__(256, 2) void k_heavy_f(const int* __restrict__ entries,
                                                    const u16* __restrict__ embb,
                                                    const u16* __restrict__ vqb,
                                                    const u16* __restrict__ qbf,
                                                    const u16* __restrict__ keb,
                                                    float* __restrict__ lg,
                                                    u16* __restrict__ numCp,
                                                    u16* __restrict__ numKp,
                                                    float* __restrict__ mLp,
                                                    float* __restrict__ denLp) {
    __shared__ __align__(16) u16 sEu[2][N * STR_E];   // 33,792 B
    __shared__ __align__(16) u16 sETu[2][64 * 136];   // 34,816 B
    __shared__ __align__(16) u16 sPu[B * STR_P];      //  5,120 B
    __shared__ float sw[EPB][B];                      //  4,096 B

    int t = threadIdx.x;
    int lane = t & 63, l = lane & 15, q = lane >> 4, w = t >> 6;
    int b0 = 16 * w;
    int sp = t & 31, n0 = t >> 5;
    int m0 = blockIdx.x * EPB;
    int bb = t & 63, y = t >> 6;

    // ---- earliest: ids(e0) + bf16 gather(e0) — flies underneath the fused logits ----
    int idc[4], idn[4];
    uint4 pfF[4];   // 4 rows x 16 B (8 bf16 per row-chunk, pre-masked)
#pragma unroll
    for (int i = 0; i < 4; ++i) idc[i] = entries[m0 * N + n0 + 8 * i];
#pragma unroll
    for (int i = 0; i < 4; ++i)
        pfF[i] = *(const uint4*)(embb + (size_t)idc[i] * D + sp * 8);

    // ---- fused logits: aL[r] = lg[b0+4q+r][m0+l]  (16 m x 64 b tile) ----
    fx4 zero4 = {0.f, 0.f, 0.f, 0.f};
    fx4 aL = zero4;
#pragma unroll
    for (int s = 0; s < 8; ++s) {
        bf16x8 a  = *(const bf16x8*)(qbf + (size_t)(b0 + l) * D + 32 * s + 8 * q);
        bf16x8 bq = *(const bf16x8*)(keb + (size_t)(m0 + l) * D + 32 * s + 8 * q);
        aL = __builtin_amdgcn_mfma_f32_16x16x32_bf16(a, bq, aL, 0, 0, 0);
    }
#pragma unroll
    for (int r = 0; r < 4; ++r)
        lg[(size_t)(b0 + 4 * q + r) * LG_LD + m0 + l] = aL[r];

    // ---- flash stats via 16-lane shuffles: mL[b], weights sw[m][b], den[b] ----
#pragma unroll
    for (int r = 0; r < 4; ++r) {
        float m_ = aL[r];
        m_ = fmaxf(m_, __shfl_xor(m_, 1));
        m_ = fmaxf(m_, __shfl_xor(m_, 2));
        m_ = fmaxf(m_, __shfl_xor(m_, 4));
        m_ = fmaxf(m_, __shfl_xor(m_, 8));
        float wv = __expf(aL[r] - m_);
        sw[l][b0 + 4 * q + r] = wv;     // entry m0+l, batch b0+4q+r (wave-private columns)
        float d_ = wv;
        d_ += __shfl_xor(d_, 1);
        d_ += __shfl_xor(d_, 2);
        d_ += __shfl_xor(d_, 4);
        d_ += __shfl_xor(d_, 8);
        if (l == 0) {
            mLp[blockIdx.x * B + b0 + 4 * q + r] = m_;
            denLp[blockIdx.x * B + b0 + 4 * q + r] = d_;
        }
    }

    // persistent vq B-fragments
    bf16x8 vqf[8];
#pragma unroll
    for (int s = 0; s < 8; ++s)
        vqf[s] = *(const bf16x8*)(vqb + (b0 + l) * D + 32 * s + 8 * q);

    fx4 acc[16];   // acc[4*bg + dtl]: batch-group bg, d-tile 4w+dtl
#pragma unroll
    for (int dt = 0; dt < 16; ++dt) acc[dt] = zero4;

    // ---- gather pipeline prologue: buf0 <- e0; pfF <- e1; idn <- ids(e2) ----
    {
#pragma unroll
        for (int i = 0; i < 4; ++i)
            *(uint4*)&sEu[0][(n0 + 8 * i) * STR_E + sp * 8] = pfF[i];
#pragma unroll
        for (int j = 0; j < 8; ++j) {
            unsigned a0 = (((unsigned*)&pfF[0])[j >> 1] >> ((j & 1) * 16)) & 0xFFFFu;
            unsigned a1 = (((unsigned*)&pfF[1])[j >> 1] >> ((j & 1) * 16)) & 0xFFFFu;
            unsigned a2 = (((unsigned*)&pfF[2])[j >> 1] >> ((j & 1) * 16)) & 0xFFFFu;
            unsigned a3 = (((unsigned*)&pfF[3])[j >> 1] >> ((j & 1) * 16)) & 0xFFFFu;
            uint2 pr = make_uint2(a0 | (a1 << 16), a2 | (a3 << 16));
            int off = (2 * sp + (j >> 2)) * 136 + (j & 3) * 32 + (n0 >> 1) * 8 + (n0 & 1) * 4;
            *(uint2*)&sETu[0][off] = pr;
        }
    }
#pragma unroll
    for (int i = 0; i < 4; ++i) idc[i] = entries[(m0 + 1) * N + n0 + 8 * i];
#pragma unroll
    for (int i = 0; i < 4; ++i)
        pfF[i] = *(const uint4*)(embb + (size_t)idc[i] * D + sp * 8);
#pragma unroll
    for (int i = 0; i < 4; ++i) idn[i] = entries[(m0 + 2) * N + n0 + 8 * i];

    int offL2 = (l >> 2) * 136 + (l & 3) * 32;   // eb base (new layout)

    // ---- entry loop: 1 syncthreads + 1 lgkm barrier per entry ----
#pragma unroll 2
    for (int e = 0; e < EPB; ++e) {
        __syncthreads();   // buf[e&1] staged; prev PV reads of buf[(e+1)&1] + sPu done
        int nxt = (e + 1) & 1;
        if (e < EPB - 1) {
            // (a) stage entry e+1 (held in pfF): write sE (b128) + sET (b64)
#pragma unroll
            for (int i = 0; i < 4; ++i)
                *(uint4*)&sEu[nxt][(n0 + 8 * i) * STR_E + sp * 8] = pfF[i];
#pragma unroll
            for (int j = 0; j < 8; ++j) {
                unsigned a0 = (((unsigned*)&pfF[0])[j >> 1] >> ((j & 1) * 16)) & 0xFFFFu;
                unsigned a1 = (((unsigned*)&pfF[1])[j >> 1] >> ((j & 1) * 16)) & 0xFFFFu;
                unsigned a2 = (((unsigned*)&pfF[2])[j >> 1] >> ((j & 1) * 16)) & 0xFFFFu;
                unsigned a3 = (((unsigned*)&pfF[3])[j >> 1] >> ((j & 1) * 16)) & 0xFFFFu;
                uint2 pr = make_uint2(a0 | (a1 << 16), a2 | (a3 << 16));
                int off = (2 * sp + (j >> 2)) * 136 + (j & 3) * 32 + (n0 >> 1) * 8 + (n0 & 1) * 4;
                *(uint2*)&sETu[nxt][off] = pr;
            }
            // (b) issue bf16 gather entry e+2 (stays in flight through this entry's compute)
            if (e < EPB - 2) {
#pragma unroll
                for (int i = 0; i < 4; ++i)
                    pfF[i] = *(const uint4*)(embb + (size_t)idn[i] * D + sp * 8);
#pragma unroll
                for (int i = 0; i < 4; ++i) idc[i] = idn[i];
                if (e < EPB - 3) {
#pragma unroll
                    for (int i = 0; i < 4; ++i) idn[i] = entries[(m0 + e + 3) * N + n0 + 8 * i];
                }
            }
        }
        // (c) compute entry e from buf[cur]
        int cur = e & 1;
        fx4 accS[2];
        accS[0] = zero4; accS[1] = zero4;
#pragma unroll
        for (int T = 0; T < 2; ++T)
#pragma unroll
            for (int s = 0; s < 8; ++s) {
                bf16x8 ea = *(const bf16x8*)&sEu[cur][(16 * T + l) * STR_E + 32 * s + 8 * q];
                accS[T] = __builtin_amdgcn_mfma_f32_16x16x32_bf16(ea, vqf[s], accS[T], 0, 0, 0);
            }
        float swb = sw[e][b0 + l];
        float mx = -INFINITY;
#pragma unroll
        for (int T = 0; T < 2; ++T)
#pragma unroll
            for (int r = 0; r < 4; ++r) mx = fmaxf(mx, accS[T][r]);
        mx = fmaxf(mx, __shfl_xor(mx, 16));
        mx = fmaxf(mx, __shfl_xor(mx, 32));
        float pe[2][4], sum = 0.f;
#pragma unroll
        for (int T = 0; T < 2; ++T)
#pragma unroll
            for (int r = 0; r < 4; ++r) {
                pe[T][r] = __expf(accS[T][r] - mx);
                sum += pe[T][r];
            }
        sum += __shfl_xor(sum, 16);
        sum += __shfl_xor(sum, 32);
        float sc = swb / sum;
#pragma unroll
        for (int T = 0; T < 2; ++T)
#pragma unroll
            for (int r = 0; r < 4; ++r) {
                int nn = 16 * T + 4 * q + r;
                int slot = 4 * (nn & 7) + (nn >> 3);
                sPu[(b0 + l) * STR_P + slot] = f2bf(pe[T][r] * sc);
            }
        BARRIER_LGKM();   // sP(e) visible to all waves (cross-wave PV reads)
        // PV wave-split: this wave owns dt = 4w+dtl for ALL batch groups
        {
            bf16x8 paA[4];
#pragma unroll
            for (int bg = 0; bg < 4; ++bg)
                paA[bg] = *(const bf16x8*)&sPu[(16 * bg + l) * STR_P + 8 * q];
#pragma unroll
            for (int dtl = 0; dtl < 4; ++dtl) {
                bf16x8 eb = *(const bf16x8*)&sETu[cur][offL2 + (4 * w + dtl) * 544 + q * 8];
#pragma unroll
                for (int bg = 0; bg < 4; ++bg)
                    acc[4 * bg + dtl] = __builtin_amdgcn_mfma_f32_16x16x32_bf16(
                        paA[bg], eb, acc[4 * bg + dtl], 0, 0, 0);
            }
        }
    }

    // ---- store numC partial: acc[4bg+dtl][r] -> b = 16bg+4q+r, d = 16(4w+dtl)+l ----
    u16* ncp = numCp + (size_t)blockIdx.x * (B * D);
#pragma unroll
    for (int bg = 0; bg < 4; ++bg)
#pragma unroll
        for (int dtl = 0; dtl < 4; ++dtl)
#pragma unroll
            for (int r = 0; r < 4; ++r)
                ncp[(16 * bg + 4 * q + r) * D + 16 * (4 * w + dtl) + l] =
                    f2bf(acc[4 * bg + dtl][r]);

    // ---- numK mini-PV: keys rows m0..m0+15, slot2(m) = 2*(m&7)+(m>>3); A zero-padded ----
    __syncthreads();   // all waves done reading sETu/sPu
    {
        int rp = t >> 5;   // 0..7
        uint4 ka = *(const uint4*)(keb + (size_t)(m0 + rp) * D + sp * 8);
        uint4 kb = *(const uint4*)(keb + (size_t)(m0 + rp + 8) * D + sp * 8);
#pragma unroll
        for (int j = 0; j < 8; ++j) {
            unsigned a0 = (((unsigned*)&ka)[j >> 1] >> ((j & 1) * 16)) & 0xFFFFu;
            unsigned a1 = (((unsigned*)&kb)[j >> 1] >> ((j & 1) * 16)) & 0xFFFFu;
            int d = 8 * sp + j;
            int sl = 2 * rp;   // slots 2rp, 2rp+1
            int off = (d >> 2) * 136 + (d & 3) * 32 + (sl >> 3) * 8 + (sl & 7);
            *(unsigned*)&sETu[0][off] = a0 | (a1 << 16);
        }
        // weights into sP (slots 0..15 = flash weights, 16..31 = 0)
#pragma unroll
        for (int i = 0; i < 4; ++i) {
            int m = 4 * i + y;
            int slot = 2 * (m & 7) + (m >> 3);
            sPu[bb * STR_P + slot] = f2bf(sw[m][bb]);
        }
        *(uint2*)&sPu[bb * STR_P + 16 + 4 * y] = make_uint2(0u, 0u);
    }
    __syncthreads();
    fx4 acc2[16];
#pragma unroll
    for (int dt = 0; dt < 16; ++dt) acc2[dt] = zero4;
    {
        bf16x8 pa2A[4];
#pragma unroll
        for (int bg = 0; bg < 4; ++bg)
            pa2A[bg] = *(const bf16x8*)&sPu[(16 * bg + l) * STR_P + 8 * q];
#pragma unroll
        for (int dtl = 0; dtl < 4; ++dtl) {
            bf16x8 eb2 = *(const bf16x8*)&sETu[0][offL2 + (4 * w + dtl) * 544 + q * 8];
#pragma unroll
            for (int bg = 0; bg < 4; ++bg)
                acc2[4 * bg + dtl] = __builtin_amdgcn_mfma_f32_16x16x32_bf16(
                    pa2A[bg], eb2, acc2[4 * bg + dtl], 0, 0, 0);
        }
    }
    u16* nkp = numKp + (size_t)blockIdx.x * (B * D);
#pragma unroll
    for (int bg = 0; bg < 4; ++bg)
#pragma unroll
        for (int dtl = 0; dtl < 4; ++dtl)
#pragma unroll
            for (int r = 0; r < 4; ++r)
                nkp[(16 * bg + 4 * q + r) * D + 16 * (4 * w + dtl) + l] =
                    f2bf(acc2[4 * bg + dtl][r]);
}

// ---- k_comb2: fused global stats + 500-way partial reduce -> o_k, comb ----
// 512 blocks: (b x 8 d-chunks). Main loop vectorized: uint2 (4 bf16), 32 stripes.
__global__ __launch_bounds__(256) void k_comb2(const u16* __restrict__ numCp,
                                               const u16* __restrict__ numKp,
                                               const float* __restrict__ mLp,
                                               const float* __restrict__ denLp,
                                               float* __restrict__ o_k,
                                               float* __restrict__ comb) {
    __shared__ float sscale[NBLK];
    __shared__ float red[256];
    __shared__ float sro[32][33], src[32][33];
    __shared__ float srden;
    int bid = blockIdx.x;
    int b = bid >> 3, d0 = (bid & 7) * 32;
    int t = threadIdx.x;
    float mx = -INFINITY;
    for (int blk = t; blk < NBLK; blk += 256) mx = fmaxf(mx, mLp[blk * B + b]);
    red[t] = mx;
    __syncthreads();
    for (int s = 128; s > 0; s >>= 1) {
        if (t < s) red[t] = fmaxf(red[t], red[t + s]);
        __syncthreads();
    }
    float Mg = red[0];
    __syncthreads();
    float ds = 0.f;
    for (int blk = t; blk < NBLK; blk += 256) {
        float sc = __expf(mLp[blk * B + b] - Mg);
        sscale[blk] = sc;
        ds += sc * denLp[blk * B + b];
    }
    red[t] = ds;
    __syncthreads();
    for (int s = 128; s > 0; s >>= 1) {
        if (t < s) red[t] += red[t + s];
        __syncthreads();
    }
    if (t == 0) srden = 1.f / red[0];
    __syncthreads();
    int v = t & 7, s = t >> 3;
    float ao[4] = {0.f, 0.f, 0.f, 0.f}, ac[4] = {0.f, 0.f, 0.f, 0.f};
    for (int blk = s; blk < NBLK; blk += 32) {
        float sc = sscale[blk];
        size_t i = (size_t)blk * (B * D) + (size_t)b * D + d0 + v * 4;
        uint2 kk = *(const uint2*)(numKp + i);
        uint2 cc = *(const uint2*)(numCp + i);
        ao[0] += sc * bf2f((u16)(kk.x & 0xFFFFu));
        ao[1] += sc * bf2f((u16)(kk.x >> 16));
        ao[2] += sc * bf2f((u16)(kk.y & 0xFFFFu));
        ao[3] += sc * bf2f((u16)(kk.y >> 16));
        ac[0] += sc * bf2f((u16)(cc.x & 0xFFFFu));
        ac[1] += sc * bf2f((u16)(cc.x >> 16));
        ac[2] += sc * bf2f((u16)(cc.y & 0xFFFFu));
        ac[3] += sc * bf2f((u16)(cc.y >> 16));
    }
#pragma unroll
    for (int k = 0; k < 4; ++k) {
        sro[s][v * 4 + k] = ao[k];
        src[s][v * 4 + k] = ac[k];
    }
    __syncthreads();
    if (t < 32) {
        float so = 0.f, sc2 = 0.f;
#pragma unroll
        for (int k2 = 0; k2 < 32; ++k2) { so += sro[k2][t]; sc2 += src[k2][t]; }
        float rd = srden;
        o_k[b * D + d0 + t] = so * rd;
        comb[b * D + d0 + t] = sc2 * rd;
    }
}

// ==================== launcher ====================

extern "C" void kernel_launch(void* const* d_in, const int* in_sizes, int n_in,
                              void* d_out, int out_size, void* d_ws, size_t ws_size,
                              hipStream_t stream) {
    const int*   keys    = (const int*)d_in[0];
    const int*   entries = (const int*)d_in[1];
    const float* query   = (const float*)d_in[2];
    const float* wordemb = (const float*)d_in[3];
    const float* qproj_w = (const float*)d_in[4];
    const float* qproj_b = (const float*)d_in[5];

    float* out  = (float*)d_out;
    float* o_k  = out;
    float* lg   = out + B * D;
    float* comb = out + B * D + B * M;

    char* wsb = (char*)d_ws;
    u16*   embb  = (u16*)wsb;                      // 25,600,000 B (bf16 table, row0=0)
    u16*   keb   = (u16*)(wsb + 25600000);         //  4,096,000 B
    u16*   qbf   = (u16*)(wsb + 29696000);         //     32,768 B
    u16*   vqb   = (u16*)(wsb + 29728768);         //     32,768 B
    u16*   numCp = (u16*)(wsb + 29761536);         // 16,384,000 B
    u16*   numKp = (u16*)(wsb + 46145536);         // 16,384,000 B
    float* mLp   = (float*)(wsb + 62529536);       //    128,000 B
    float* denLp = (float*)(wsb + 62657536);       //    128,000 B  (end 62,785,536)

    k_prep_all<<<7322, 256, 0, stream>>>(keys, wordemb, query, qproj_w, qproj_b,
                                         embb, qbf, keb, vqb);
    k_heavy_f<<<NBLK, 256, 0, stream>>>(entries, embb, vqb, qbf, keb, lg,
                                        numCp, numKp, mLp, denLp);
    k_comb2<<<512, 256, 0, stream>>>(numCp, numKp, mLp, denLp, o_k, comb);
}

// Round 11
// 164.953 us; speedup vs baseline: 1.5825x; 1.0199x over previous
//
#include <hip/hip_runtime.h>
#include <math.h>

#define B 64
#define D 256
#define M 8000
#define N 32
#define LG_LD 8000
#define EPB 16          // entries per block (flash k_heavy)
#define NBLK (M / EPB)  // 500
#define VOCAB 50000

typedef unsigned short u16;
typedef __bf16 bf16x8 __attribute__((ext_vector_type(8)));
typedef float fx4 __attribute__((ext_vector_type(4)));

#define STR_E  264   // u16 stride of sE rows (n-major)  [ea reads: bank-uniform, proven]
#define STR_P  40    // u16 stride of sP rows (b-major)  [pa reads: bank-uniform]
// sET layout (R9 + R10 swizzle): u16 idx of (d, slot) =
//   (d>>2)*136 + (d&3)*32 + (((sl>>3) ^ ((d>>5)&3))<<3) + (sl&7)
// Each 16B block = one d, slots 8b..8b+7; the XOR permutes the 4 blocks within a
// 32-u16 span, so write (d=8sp+j: key=(sp>>2)&3) spreads banks 4-way -> free, and
// read (d=16dt+l: key=(dt>>1)&3, compile-time per dt) just adjusts its base —
// block CONTENT (slot order, MFMA k-order) is unchanged.
// entry-phase slot = sigma(n) = 4*(n&7) + (n>>3); key-phase slot2(m) = 2*(m&7) + (m>>3)

static __device__ __forceinline__ u16 f2bf(float x) {
    unsigned int u = __float_as_uint(x);
    u += 0x7FFFu + ((u >> 16) & 1u);
    return (u16)(u >> 16);
}
static __device__ __forceinline__ float bf2f(u16 h) {
    return __uint_as_float(((unsigned)h) << 16);
}
static __device__ __forceinline__ uint4 pack8(float4 va, float4 vb, float msk) {
    unsigned p0 = (unsigned)f2bf(va.x * msk) | ((unsigned)f2bf(va.y * msk) << 16);
    unsigned p1 = (unsigned)f2bf(va.z * msk) | ((unsigned)f2bf(va.w * msk) << 16);
    unsigned p2 = (unsigned)f2bf(vb.x * msk) | ((unsigned)f2bf(vb.y * msk) << 16);
    unsigned p3 = (unsigned)f2bf(vb.z * msk) | ((unsigned)f2bf(vb.w * msk) << 16);
    return make_uint4(p0, p1, p2, p3);
}

// lgkm-only barrier: LDS visibility without draining in-flight global loads.
#define BARRIER_LGKM() do {                                   \
    asm volatile("s_waitcnt lgkmcnt(0)" ::: "memory");        \
    __builtin_amdgcn_s_barrier();                             \
    asm volatile("" ::: "memory");                            \
} while (0)

// ---- k_prep_all: ONE kernel, four independent block ranges:
//      0..6249    : emb fp32 -> embb bf16 stream (row 0 zeroed = pre-applied pad mask)
//      6250..7249 : keb gather straight from fp32 emb (mask+pack here)
//      7250..7257 : qbf conv
//      7258..7321 : vq proj
__global__ __launch_bounds__(256) void k_prep_all(const int* __restrict__ keys,
                                                  const float* __restrict__ emb,
                                                  const float* __restrict__ q,
                                                  const float* __restrict__ W,
                                                  const float* __restrict__ bias,
                                                  u16* __restrict__ embb,
                                                  u16* __restrict__ qbf,
                                                  u16* __restrict__ keb,
                                                  u16* __restrict__ vqb) {
    __shared__ float qs[D];
    int t = threadIdx.x, bid = blockIdx.x;
    if (bid < 6250) {
        size_t idx = (size_t)bid * 2048 + (size_t)t * 8;
        float4 v0 = *(const float4*)(emb + idx);
        float4 v1 = *(const float4*)(emb + idx + 4);
        float msk = (idx < D) ? 0.f : 1.f;   // row 0 = PAD row -> zeros
        uint4 pk = pack8(v0, v1, msk);
        *(uint4*)(embb + idx) = pk;
    } else if (bid < 7250) {
        int c = (bid - 6250) * 256 + t;   // 8000*32 chunks of 8 elems
        int j = c >> 5, sp = c & 31;
        int id = keys[j];
        const float* rp = emb + (size_t)id * D + sp * 8;
        float4 v0 = *(const float4*)rp;
        float4 v1 = *(const float4*)(rp + 4);
        float msk = (id != 0) ? 1.f : 0.f;
        uint4 pk = pack8(v0, v1, msk);
        *(uint4*)(keb + (size_t)j * D + sp * 8) = pk;
    } else if (bid < 7258) {
        size_t idx = (size_t)(bid - 7250) * 2048 + (size_t)t * 8;
        float4 v0 = *(const float4*)(q + idx);
        float4 v1 = *(const float4*)(q + idx + 4);
        uint4 pk = pack8(v0, v1, 1.f);
        *(uint4*)(qbf + idx) = pk;
    } else {
        int b = bid - 7258;
        qs[t] = q[b * D + t];
        __syncthreads();
        const float* wr = W + t * D;
        float acc = bias[t];
#pragma unroll 8
        for (int k = 0; k < D; k += 4) {
            float4 w4 = *(const float4*)(wr + k);
            acc += qs[k] * w4.x + qs[k + 1] * w4.y + qs[k + 2] * w4.z + qs[k + 3] * w4.w;
        }
        vqb[b * D + t] = f2bf(acc);
    }
}

// ---- k_heavy_f: fused logits + flash stats + per-entry value attention + numK mini-PV.
//      R9 base (EPB=16 dbuf, PV wave-split, bank-uniform eb).  ROUND 10: sET
//      write-side block swizzle (header) removes the last provable conflict class
//      (staging writes were 4-way: bank = 8(sp&3)+2(n0&1) -> 8 lanes/2-bank pair).
__global__ __launch_bounds__(256, 2) void k_heavy_f(const int* __restrict__ entries,
                                                    const u16* __restrict__ embb,
                                                    const u16* __restrict__ vqb,
                                                    const u16* __restrict__ qbf,
                                                    const u16* __restrict__ keb,
                                                    float* __restrict__ lg,
                                                    u16* __restrict__ numCp,
                                                    u16* __restrict__ numKp,
                                                    float* __restrict__ mLp,
                                                    float* __restrict__ denLp) {
    __shared__ __align__(16) u16 sEu[2][N * STR_E];   // 33,792 B
    __shared__ __align__(16) u16 sETu[2][64 * 136];   // 34,816 B
    __shared__ __align__(16) u16 sPu[B * STR_P];      //  5,120 B
    __shared__ float sw[EPB][B];                      //  4,096 B

    int t = threadIdx.x;
    int lane = t & 63, l = lane & 15, q = lane >> 4, w = t >> 6;
    int b0 = 16 * w;
    int sp = t & 31, n0 = t >> 5;
    int m0 = blockIdx.x * EPB;
    int bb = t & 63, y = t >> 6;
    int swzk = (sp >> 2) & 3;   // sET write swizzle key = (d>>5)&3 for d = 8sp+j

    // ---- earliest: ids(e0) + bf16 gather(e0) — flies underneath the fused logits ----
    int idc[4], idn[4];
    uint4 pfF[4];   // 4 rows x 16 B (8 bf16 per row-chunk, pre-masked)
#pragma unroll
    for (int i = 0; i < 4; ++i) idc[i] = entries[m0 * N + n0 + 8 * i];
#pragma unroll
    for (int i = 0; i < 4; ++i)
        pfF[i] = *(const uint4*)(embb + (size_t)idc[i] * D + sp * 8);

    // ---- fused logits: aL[r] = lg[b0+4q+r][m0+l]  (16 m x 64 b tile) ----
    fx4 zero4 = {0.f, 0.f, 0.f, 0.f};
    fx4 aL = zero4;
#pragma unroll
    for (int s = 0; s < 8; ++s) {
        bf16x8 a  = *(const bf16x8*)(qbf + (size_t)(b0 + l) * D + 32 * s + 8 * q);
        bf16x8 bq = *(const bf16x8*)(keb + (size_t)(m0 + l) * D + 32 * s + 8 * q);
        aL = __builtin_amdgcn_mfma_f32_16x16x32_bf16(a, bq, aL, 0, 0, 0);
    }
#pragma unroll
    for (int r = 0; r < 4; ++r)
        lg[(size_t)(b0 + 4 * q + r) * LG_LD + m0 + l] = aL[r];

    // ---- flash stats via 16-lane shuffles: mL[b], weights sw[m][b], den[b] ----
#pragma unroll
    for (int r = 0; r < 4; ++r) {
        float m_ = aL[r];
        m_ = fmaxf(m_, __shfl_xor(m_, 1));
        m_ = fmaxf(m_, __shfl_xor(m_, 2));
        m_ = fmaxf(m_, __shfl_xor(m_, 4));
        m_ = fmaxf(m_, __shfl_xor(m_, 8));
        float wv = __expf(aL[r] - m_);
        sw[l][b0 + 4 * q + r] = wv;     // entry m0+l, batch b0+4q+r (wave-private columns)
        float d_ = wv;
        d_ += __shfl_xor(d_, 1);
        d_ += __shfl_xor(d_, 2);
        d_ += __shfl_xor(d_, 4);
        d_ += __shfl_xor(d_, 8);
        if (l == 0) {
            mLp[blockIdx.x * B + b0 + 4 * q + r] = m_;
            denLp[blockIdx.x * B + b0 + 4 * q + r] = d_;
        }
    }

    // persistent vq B-fragments
    bf16x8 vqf[8];
#pragma unroll
    for (int s = 0; s < 8; ++s)
        vqf[s] = *(const bf16x8*)(vqb + (b0 + l) * D + 32 * s + 8 * q);

    fx4 acc[16];   // acc[4*bg + dtl]: batch-group bg, d-tile 4w+dtl
#pragma unroll
    for (int dt = 0; dt < 16; ++dt) acc[dt] = zero4;

    // ---- gather pipeline prologue: buf0 <- e0; pfF <- e1; idn <- ids(e2) ----
    {
#pragma unroll
        for (int i = 0; i < 4; ++i)
            *(uint4*)&sEu[0][(n0 + 8 * i) * STR_E + sp * 8] = pfF[i];
#pragma unroll
        for (int j = 0; j < 8; ++j) {
            unsigned a0 = (((unsigned*)&pfF[0])[j >> 1] >> ((j & 1) * 16)) & 0xFFFFu;
            unsigned a1 = (((unsigned*)&pfF[1])[j >> 1] >> ((j & 1) * 16)) & 0xFFFFu;
            unsigned a2 = (((unsigned*)&pfF[2])[j >> 1] >> ((j & 1) * 16)) & 0xFFFFu;
            unsigned a3 = (((unsigned*)&pfF[3])[j >> 1] >> ((j & 1) * 16)) & 0xFFFFu;
            uint2 pr = make_uint2(a0 | (a1 << 16), a2 | (a3 << 16));
            int off = (2 * sp + (j >> 2)) * 136 + (j & 3) * 32 +
                      (((n0 >> 1) ^ swzk) << 3) + (n0 & 1) * 4;
            *(uint2*)&sETu[0][off] = pr;
        }
    }
#pragma unroll
    for (int i = 0; i < 4; ++i) idc[i] = entries[(m0 + 1) * N + n0 + 8 * i];
#pragma unroll
    for (int i = 0; i < 4; ++i)
        pfF[i] = *(const uint4*)(embb + (size_t)idc[i] * D + sp * 8);
#pragma unroll
    for (int i = 0; i < 4; ++i) idn[i] = entries[(m0 + 2) * N + n0 + 8 * i];

    int offL2 = (l >> 2) * 136 + (l & 3) * 32;   // eb base (d-part; q-block added per dt)

    // ---- entry loop: 1 syncthreads + 1 lgkm barrier per entry ----
#pragma unroll 2
    for (int e = 0; e < EPB; ++e) {
        __syncthreads();   // buf[e&1] staged; prev PV reads of buf[(e+1)&1] + sPu done
        int nxt = (e + 1) & 1;
        if (e < EPB - 1) {
            // (a) stage entry e+1 (held in pfF): write sE (b128) + sET (b64, swizzled)
#pragma unroll
            for (int i = 0; i < 4; ++i)
                *(uint4*)&sEu[nxt][(n0 + 8 * i) * STR_E + sp * 8] = pfF[i];
#pragma unroll
            for (int j = 0; j < 8; ++j) {
                unsigned a0 = (((unsigned*)&pfF[0])[j >> 1] >> ((j & 1) * 16)) & 0xFFFFu;
                unsigned a1 = (((unsigned*)&pfF[1])[j >> 1] >> ((j & 1) * 16)) & 0xFFFFu;
                unsigned a2 = (((unsigned*)&pfF[2])[j >> 1] >> ((j & 1) * 16)) & 0xFFFFu;
                unsigned a3 = (((unsigned*)&pfF[3])[j >> 1] >> ((j & 1) * 16)) & 0xFFFFu;
                uint2 pr = make_uint2(a0 | (a1 << 16), a2 | (a3 << 16));
                int off = (2 * sp + (j >> 2)) * 136 + (j & 3) * 32 +
                          (((n0 >> 1) ^ swzk) << 3) + (n0 & 1) * 4;
                *(uint2*)&sETu[nxt][off] = pr;
            }
            // (b) issue bf16 gather entry e+2 (stays in flight through this entry's compute)
            if (e < EPB - 2) {
#pragma unroll
                for (int i = 0; i < 4; ++i)
                    pfF[i] = *(const uint4*)(embb + (size_t)idn[i] * D + sp * 8);
#pragma unroll
                for (int i = 0; i < 4; ++i) idc[i] = idn[i];
                if (e < EPB - 3) {
#pragma unroll
                    for (int i = 0; i < 4; ++i) idn[i] = entries[(m0 + e + 3) * N + n0 + 8 * i];
                }
            }
        }
        // (c) compute entry e from buf[cur]
        int cur = e & 1;
        fx4 accS[2];
        accS[0] = zero4; accS[1] = zero4;
#pragma unroll
        for (int T = 0; T < 2; ++T)
#pragma unroll
            for (int s = 0; s < 8; ++s) {
                bf16x8 ea = *(const bf16x8*)&sEu[cur][(16 * T + l) * STR_E + 32 * s + 8 * q];
                accS[T] = __builtin_amdgcn_mfma_f32_16x16x32_bf16(ea, vqf[s], accS[T], 0, 0, 0);
            }
        float swb = sw[e][b0 + l];
        float mx = -INFINITY;
#pragma unroll
        for (int T = 0; T < 2; ++T)
#pragma unroll
            for (int r = 0; r < 4; ++r) mx = fmaxf(mx, accS[T][r]);
        mx = fmaxf(mx, __shfl_xor(mx, 16));
        mx = fmaxf(mx, __shfl_xor(mx, 32));
        float pe[2][4], sum = 0.f;
#pragma unroll
        for (int T = 0; T < 2; ++T)
#pragma unroll
            for (int r = 0; r < 4; ++r) {
                pe[T][r] = __expf(accS[T][r] - mx);
                sum += pe[T][r];
            }
        sum += __shfl_xor(sum, 16);
        sum += __shfl_xor(sum, 32);
        float sc = swb / sum;
#pragma unroll
        for (int T = 0; T < 2; ++T)
#pragma unroll
            for (int r = 0; r < 4; ++r) {
                int nn = 16 * T + 4 * q + r;
                int slot = 4 * (nn & 7) + (nn >> 3);
                sPu[(b0 + l) * STR_P + slot] = f2bf(pe[T][r] * sc);
            }
        BARRIER_LGKM();   // sP(e) visible to all waves (cross-wave PV reads)
        // PV wave-split: this wave owns dt = 4w+dtl for ALL batch groups
        {
            bf16x8 paA[4];
#pragma unroll
            for (int bg = 0; bg < 4; ++bg)
                paA[bg] = *(const bf16x8*)&sPu[(16 * bg + l) * STR_P + 8 * q];
#pragma unroll
            for (int dtl = 0; dtl < 4; ++dtl) {
                int qs8 = (q ^ ((2 * w + (dtl >> 1)) & 3)) * 8;   // block key (dt>>1)&3
                bf16x8 eb = *(const bf16x8*)&sETu[cur][offL2 + (4 * w + dtl) * 544 + qs8];
#pragma unroll
                for (int bg = 0; bg < 4; ++bg)
                    acc[4 * bg + dtl] = __builtin_amdgcn_mfma_f32_16x16x32_bf16(
                        paA[bg], eb, acc[4 * bg + dtl], 0, 0, 0);
            }
        }
    }

    // ---- store numC partial: acc[4bg+dtl][r] -> b = 16bg+4q+r, d = 16(4w+dtl)+l ----
    u16* ncp = numCp + (size_t)blockIdx.x * (B * D);
#pragma unroll
    for (int bg = 0; bg < 4; ++bg)
#pragma unroll
        for (int dtl = 0; dtl < 4; ++dtl)
#pragma unroll
            for (int r = 0; r < 4; ++r)
                ncp[(16 * bg + 4 * q + r) * D + 16 * (4 * w + dtl) + l] =
                    f2bf(acc[4 * bg + dtl][r]);

    // ---- numK mini-PV: keys rows m0..m0+15, slot2(m) = 2*(m&7)+(m>>3); A zero-padded ----
    __syncthreads();   // all waves done reading sETu/sPu
    {
        int rp = t >> 5;   // 0..7
        uint4 ka = *(const uint4*)(keb + (size_t)(m0 + rp) * D + sp * 8);
        uint4 kb = *(const uint4*)(keb + (size_t)(m0 + rp + 8) * D + sp * 8);
#pragma unroll
        for (int j = 0; j < 8; ++j) {
            unsigned a0 = (((unsigned*)&ka)[j >> 1] >> ((j & 1) * 16)) & 0xFFFFu;
            unsigned a1 = (((unsigned*)&kb)[j >> 1] >> ((j & 1) * 16)) & 0xFFFFu;
            int d = 8 * sp + j;
            int sl = 2 * rp;   // slots 2rp, 2rp+1 (same 16B block: 2rp even)
            int off = (d >> 2) * 136 + (d & 3) * 32 +
                      ((((sl >> 3)) ^ swzk) << 3) + (sl & 7);
            *(unsigned*)&sETu[0][off] = a0 | (a1 << 16);
        }
        // weights into sP (slots 0..15 = flash weights, 16..31 = 0)
#pragma unroll
        for (int i = 0; i < 4; ++i) {
            int m = 4 * i + y;
            int slot = 2 * (m & 7) + (m >> 3);
            sPu[bb * STR_P + slot] = f2bf(sw[m][bb]);
        }
        *(uint2*)&sPu[bb * STR_P + 16 + 4 * y] = make_uint2(0u, 0u);
    }
    __syncthreads();
    fx4 acc2[16];
#pragma unroll
    for (int dt = 0; dt < 16; ++dt) acc2[dt] = zero4;
    {
        bf16x8 pa2A[4];
#pragma unroll
        for (int bg = 0; bg < 4; ++bg)
            pa2A[bg] = *(const bf16x8*)&sPu[(16 * bg + l) * STR_P + 8 * q];
#pragma unroll
        for (int dtl = 0; dtl < 4; ++dtl) {
            int qs8 = (q ^ ((2 * w + (dtl >> 1)) & 3)) * 8;
            bf16x8 eb2 = *(const bf16x8*)&sETu[0][offL2 + (4 * w + dtl) * 544 + qs8];
#pragma unroll
            for (int bg = 0; bg < 4; ++bg)
                acc2[4 * bg + dtl] = __builtin_amdgcn_mfma_f32_16x16x32_bf16(
                    pa2A[bg], eb2, acc2[4 * bg + dtl], 0, 0, 0);
        }
    }
    u16* nkp = numKp + (size_t)blockIdx.x * (B * D);
#pragma unroll
    for (int bg = 0; bg < 4; ++bg)
#pragma unroll
        for (int dtl = 0; dtl < 4; ++dtl)
#pragma unroll
            for (int r = 0; r < 4; ++r)
                nkp[(16 * bg + 4 * q + r) * D + 16 * (4 * w + dtl) + l] =
                    f2bf(acc2[4 * bg + dtl][r]);
}

// ---- k_comb2: fused global stats + 500-way partial reduce -> o_k, comb ----
// 512 blocks: (b x 8 d-chunks). Main loop vectorized: uint2 (4 bf16), 32 stripes.
__global__ __launch_bounds__(256) void k_comb2(const u16* __restrict__ numCp,
                                               const u16* __restrict__ numKp,
                                               const float* __restrict__ mLp,
                                               const float* __restrict__ denLp,
                                               float* __restrict__ o_k,
                                               float* __restrict__ comb) {
    __shared__ float sscale[NBLK];
    __shared__ float red[256];
    __shared__ float sro[32][33], src[32][33];
    __shared__ float srden;
    int bid = blockIdx.x;
    int b = bid >> 3, d0 = (bid & 7) * 32;
    int t = threadIdx.x;
    float mx = -INFINITY;
    for (int blk = t; blk < NBLK; blk += 256) mx = fmaxf(mx, mLp[blk * B + b]);
    red[t] = mx;
    __syncthreads();
    for (int s = 128; s > 0; s >>= 1) {
        if (t < s) red[t] = fmaxf(red[t], red[t + s]);
        __syncthreads();
    }
    float Mg = red[0];
    __syncthreads();
    float ds = 0.f;
    for (int blk = t; blk < NBLK; blk += 256) {
        float sc = __expf(mLp[blk * B + b] - Mg);
        sscale[blk] = sc;
        ds += sc * denLp[blk * B + b];
    }
    red[t] = ds;
    __syncthreads();
    for (int s = 128; s > 0; s >>= 1) {
        if (t < s) red[t] += red[t + s];
        __syncthreads();
    }
    if (t == 0) srden = 1.f / red[0];
    __syncthreads();
    int v = t & 7, s = t >> 3;
    float ao[4] = {0.f, 0.f, 0.f, 0.f}, ac[4] = {0.f, 0.f, 0.f, 0.f};
    for (int blk = s; blk < NBLK; blk += 32) {
        float sc = sscale[blk];
        size_t i = (size_t)blk * (B * D) + (size_t)b * D + d0 + v * 4;
        uint2 kk = *(const uint2*)(numKp + i);
        uint2 cc = *(const uint2*)(numCp + i);
        ao[0] += sc * bf2f((u16)(kk.x & 0xFFFFu));
        ao[1] += sc * bf2f((u16)(kk.x >> 16));
        ao[2] += sc * bf2f((u16)(kk.y & 0xFFFFu));
        ao[3] += sc * bf2f((u16)(kk.y >> 16));
        ac[0] += sc * bf2f((u16)(cc.x & 0xFFFFu));
        ac[1] += sc * bf2f((u16)(cc.x >> 16));
        ac[2] += sc * bf2f((u16)(cc.y & 0xFFFFu));
        ac[3] += sc * bf2f((u16)(cc.y >> 16));
    }
#pragma unroll
    for (int k = 0; k < 4; ++k) {
        sro[s][v * 4 + k] = ao[k];
        src[s][v * 4 + k] = ac[k];
    }
    __syncthreads();
    if (t < 32) {
        float so = 0.f, sc2 = 0.f;
#pragma unroll
        for (int k2 = 0; k2 < 32; ++k2) { so += sro[k2][t]; sc2 += src[k2][t]; }
        float rd = srden;
        o_k[b * D + d0 + t] = so * rd;
        comb[b * D + d0 + t] = sc2 * rd;
    }
}

// ==================== launcher ====================

extern "C" void kernel_launch(void* const* d_in, const int* in_sizes, int n_in,
                              void* d_out, int out_size, void* d_ws, size_t ws_size,
                              hipStream_t stream) {
    const int*   keys    = (const int*)d_in[0];
    const int*   entries = (const int*)d_in[1];
    const float* query   = (const float*)d_in[2];
    const float* wordemb = (const float*)d_in[3];
    const float* qproj_w = (const float*)d_in[4];
    const float* qproj_b = (const float*)d_in[5];

    float* out  = (float*)d_out;
    float* o_k  = out;
    float* lg   = out + B * D;
    float* comb = out + B * D + B * M;

    char* wsb = (char*)d_ws;
    u16*   embb  = (u16*)wsb;                      // 25,600,000 B (bf16 table, row0=0)
    u16*   keb   = (u16*)(wsb + 25600000);         //  4,096,000 B
    u16*   qbf   = (u16*)(wsb + 29696000);         //     32,768 B
    u16*   vqb   = (u16*)(wsb + 29728768);         //     32,768 B
    u16*   numCp = (u16*)(wsb + 29761536);         // 16,384,000 B
    u16*   numKp = (u16*)(wsb + 46145536);         // 16,384,000 B
    float* mLp   = (float*)(wsb + 62529536);       //    128,000 B
    float* denLp = (float*)(wsb + 62657536);       //    128,000 B  (end 62,785,536)

    k_prep_all<<<7322, 256, 0, stream>>>(keys, wordemb, query, qproj_w, qproj_b,
                                         embb, qbf, keb, vqb);
    k_heavy_f<<<NBLK, 256, 0, stream>>>(entries, embb, vqb, qbf, keb, lg,
                                        numCp, numKp, mLp, denLp);
    k_comb2<<<512, 256, 0, stream>>>(numCp, numKp, mLp, denLp, o_k, comb);
}